// Round 8
// baseline (259.935 us; speedup 1.0000x reference)
//
#include <hip/hip_runtime.h>
#include <math.h>

#define B_    32
#define C_    128
#define N_    64
#define HID_  256
#define PIX_  4096
#define STEEP 50.0f
#define INV_PI 0.318309886183790671f
#define LDH   272  // LDS row pitch (u16): 32 h1 chunks (256) + 16 pad; x tile time-shares cols 128..255
#define LDX   72   // k5 pitch

typedef unsigned short u16;
typedef unsigned int u32;
typedef unsigned long long u64;
typedef __attribute__((ext_vector_type(8))) short bf16x8;
typedef __attribute__((ext_vector_type(4))) float f32x4;

__device__ __forceinline__ u16 f2bf(float f) {
    unsigned int u = __builtin_bit_cast(unsigned int, f);
    unsigned int r = (u + 0x7FFFu + ((u >> 16) & 1u)) >> 16;
    return (u16)r;
}
__device__ __forceinline__ float bf2f(u16 h) {
    unsigned int u = ((unsigned int)h) << 16;
    return __builtin_bit_cast(float, u);
}
// HW packed f32->bf16 (RNE, bit-identical to f2bf): lo16 = bf16(a), hi16 = bf16(b).
// No builtin on gfx950 -> inline asm (T12 recipe). Pure VALU, safe to schedule.
__device__ __forceinline__ u32 cvtpk(float a, float b) {
    u32 r;
    asm("v_cvt_pk_bf16_f32 %0, %1, %2" : "=v"(r) : "v"(a), "v"(b));
    return r;
}
__device__ __forceinline__ float lo_f(u32 h) {   // f32 of low bf16
    return __builtin_bit_cast(float, h << 16);
}
__device__ __forceinline__ float hi_f(u32 h) {   // f32 of high bf16
    return __builtin_bit_cast(float, h & 0xFFFF0000u);
}

// swizzled LDS indices (chunk = 8 u16 = 16 B, rotated by row for bank spread)
__device__ __forceinline__ int h1_idx(int p, int k) {
    return p * LDH + (((k >> 3) + (p & 7)) & 31) * 8 + (k & 7);
}
// R7: rotation (p>>2)&7 — staging writes have p-stride 4; this gives 8 rotations
// (2-way = free) where (p&7) collapsed to 2 (8-way, 11M conflicts). Measured fix.
__device__ __forceinline__ int x_idx(int p, int k) {
    return p * LDH + 128 + (((k >> 3) + ((p >> 2) & 7)) & 15) * 8 + (k & 7);
}

// ---------------- Kprep: decompose weights into bf16 hi/lo + init col_s ----------------
__global__ void k_prep(const float* __restrict__ w1, const float* __restrict__ w2,
                       u16* __restrict__ w1h, u16* __restrict__ w1l,
                       u16* __restrict__ w2h, u16* __restrict__ w2l,
                       float* __restrict__ col_s, const float* __restrict__ b_col) {
    int i = blockIdx.x * 256 + threadIdx.x;
    if (i < B_ * N_) col_s[i] = b_col[0];
    if (i < HID_ * C_) {
        float v = w1[i];
        u16 h = f2bf(v);
        w1h[i] = h;
        w1l[i] = f2bf(v - bf2f(h));
    } else {
        int j = i - HID_ * C_;
        if (j < HID_ * HID_) {
            float v = w2[j];
            u16 h = f2bf(v);
            w2h[j] = h;
            w2l[j] = f2bf(v - bf2f(h));
        }
    }
}

// ---------------- K12: fused conv1+conv2+scores, 64-px tile, 8 waves/block ----------------
__global__ __launch_bounds__(512) void k12_fused(
    const float* __restrict__ x,
    const u16* __restrict__ w1h, const u16* __restrict__ w1l,
    const float* __restrict__ b1,
    const u16* __restrict__ w2h, const u16* __restrict__ w2l,
    const float* __restrict__ b2, const float* __restrict__ w_row,
    const float* __restrict__ b_row, const float* __restrict__ w_col,
    float* __restrict__ row_s, float* __restrict__ col_s) {
    __shared__ __align__(16) u16 Lh[64 * LDH];   // 34816 B (h1 hi / x hi staging)
    __shared__ __align__(16) u16 Ll[64 * LDH];   // 34816 B (h1 lo / x lo staging)
    __shared__ float col_red[64];
    __shared__ float row_red;

    const int t = threadIdx.x;
    const int l = t & 63, w = t >> 6;            // w 0..7
    const int col = l & 15, q = l >> 4;
    const int hrow = blockIdx.x;
    const int b = blockIdx.y;
    const float* xb = x + (size_t)b * C_ * PIX_ + hrow * 64;

    if (t < 64) col_red[t] = 0.f;
    if (t == 0) row_red = 0.f;

    // ---- stage FULL x tile [64 p][128 c] -> swizzled cols 128..255 (one barrier) ----
    // cvt_pk packs the (c, c+1) channel pair straight into the LDS word.
    {
        const int pt = t & 15, ct = t >> 4;      // ct 0..31
#pragma unroll
        for (int cc = 0; cc < 2; cc++) {
            const int c = cc * 64 + 2 * ct;
            float4 v0 = *(const float4*)&xb[(size_t)c * PIX_ + pt * 4];
            float4 v1 = *(const float4*)&xb[(size_t)(c + 1) * PIX_ + pt * 4];
            float a0[4] = {v0.x, v0.y, v0.z, v0.w};
            float a1[4] = {v1.x, v1.y, v1.z, v1.w};
#pragma unroll
            for (int j = 0; j < 4; j++) {
                int p = pt * 4 + j;
                u32 hu = cvtpk(a0[j], a1[j]);
                u32 lu = cvtpk(a0[j] - lo_f(hu), a1[j] - hi_f(hu));
                int idx = x_idx(p, c);
                *(u32*)&Lh[idx] = hu;
                *(u32*)&Ll[idx] = lu;
            }
        }
    }
    __syncthreads();

    // ---- conv1: 96 MFMAs/wave, pipelined A (global) + B (LDS) ----
    f32x4 acc[2][4];
#pragma unroll
    for (int i = 0; i < 2; i++)
#pragma unroll
        for (int j = 0; j < 4; j++) acc[i][j] = (f32x4){0.f, 0.f, 0.f, 0.f};

    bf16x8 ah[2], al_[2];
#pragma unroll
    for (int mf = 0; mf < 2; mf++) {
        size_t ro = (size_t)(32 * w + 16 * mf + col) * C_ + q * 8;
        ah[mf] = *(const bf16x8*)&w1h[ro];
        al_[mf] = *(const bf16x8*)&w1l[ro];
    }
#pragma unroll
    for (int kc = 0; kc < 4; kc++) {
        bf16x8 bh[4], bl[4];
#pragma unroll
        for (int nt = 0; nt < 4; nt++) {
            int idx = x_idx(nt * 16 + col, kc * 32 + q * 8);
            bh[nt] = *(const bf16x8*)&Lh[idx];
            bl[nt] = *(const bf16x8*)&Ll[idx];
        }
        bf16x8 ahn[2], aln[2];
        const int kn = (kc + 1) & 3;
#pragma unroll
        for (int mf = 0; mf < 2; mf++) {
            size_t ro = (size_t)(32 * w + 16 * mf + col) * C_ + kn * 32 + q * 8;
            ahn[mf] = *(const bf16x8*)&w1h[ro];
            aln[mf] = *(const bf16x8*)&w1l[ro];
        }
#pragma unroll
        for (int mf = 0; mf < 2; mf++)
#pragma unroll
            for (int nt = 0; nt < 4; nt++) {
                acc[mf][nt] = __builtin_amdgcn_mfma_f32_16x16x32_bf16(ah[mf], bh[nt], acc[mf][nt], 0, 0, 0);
                acc[mf][nt] = __builtin_amdgcn_mfma_f32_16x16x32_bf16(ah[mf], bl[nt], acc[mf][nt], 0, 0, 0);
                acc[mf][nt] = __builtin_amdgcn_mfma_f32_16x16x32_bf16(al_[mf], bh[nt], acc[mf][nt], 0, 0, 0);
            }
#pragma unroll
        for (int mf = 0; mf < 2; mf++) { ah[mf] = ahn[mf]; al_[mf] = aln[mf]; }
    }

    // prefetch conv2's first A-frags before the barrier
    bf16x8 ah2[2], al2[2];
#pragma unroll
    for (int mf = 0; mf < 2; mf++) {
        size_t ro = (size_t)(32 * w + 16 * mf + col) * HID_ + q * 8;
        ah2[mf] = *(const bf16x8*)&w2h[ro];
        al2[mf] = *(const bf16x8*)&w2l[ro];
    }
    __syncthreads();   // all x-frag reads done; rows can be overwritten with h1

    // ---- conv1 epilogue: relu(acc+b1) -> swizzled h1 hi/lo (cvt_pk packed) ----
#pragma unroll
    for (int mf = 0; mf < 2; mf++) {
        int o = 32 * w + 16 * mf + q * 4;
        float bias[4];
#pragma unroll
        for (int r = 0; r < 4; r++) bias[r] = b1[o + r];
#pragma unroll
        for (int nt = 0; nt < 4; nt++) {
            int p = nt * 16 + col;
            float v0 = fmaxf(acc[mf][nt][0] + bias[0], 0.f);
            float v1 = fmaxf(acc[mf][nt][1] + bias[1], 0.f);
            float v2 = fmaxf(acc[mf][nt][2] + bias[2], 0.f);
            float v3 = fmaxf(acc[mf][nt][3] + bias[3], 0.f);
            u32 h01 = cvtpk(v0, v1), h23 = cvtpk(v2, v3);
            u32 l01 = cvtpk(v0 - lo_f(h01), v1 - hi_f(h01));
            u32 l23 = cvtpk(v2 - lo_f(h23), v3 - hi_f(h23));
            int idx = h1_idx(p, o);
            *(u64*)&Lh[idx] = (u64)h01 | ((u64)h23 << 32);
            *(u64*)&Ll[idx] = (u64)l01 | ((u64)l23 << 32);
        }
    }
    __syncthreads();

    // ---- conv2: 192 MFMAs/wave, pipelined ----
    f32x4 acc2[2][4];
#pragma unroll
    for (int i = 0; i < 2; i++)
#pragma unroll
        for (int j = 0; j < 4; j++) acc2[i][j] = (f32x4){0.f, 0.f, 0.f, 0.f};

#pragma unroll
    for (int kc = 0; kc < 8; kc++) {
        bf16x8 bh[4], bl[4];
#pragma unroll
        for (int nt = 0; nt < 4; nt++) {
            int idx = h1_idx(nt * 16 + col, kc * 32 + q * 8);
            bh[nt] = *(const bf16x8*)&Lh[idx];
            bl[nt] = *(const bf16x8*)&Ll[idx];
        }
        bf16x8 ahn[2], aln[2];
        const int kn = (kc + 1) & 7;
#pragma unroll
        for (int mf = 0; mf < 2; mf++) {
            size_t ro = (size_t)(32 * w + 16 * mf + col) * HID_ + kn * 32 + q * 8;
            ahn[mf] = *(const bf16x8*)&w2h[ro];
            aln[mf] = *(const bf16x8*)&w2l[ro];
        }
#pragma unroll
        for (int mf = 0; mf < 2; mf++)
#pragma unroll
            for (int nt = 0; nt < 4; nt++) {
                acc2[mf][nt] = __builtin_amdgcn_mfma_f32_16x16x32_bf16(ah2[mf], bh[nt], acc2[mf][nt], 0, 0, 0);
                acc2[mf][nt] = __builtin_amdgcn_mfma_f32_16x16x32_bf16(ah2[mf], bl[nt], acc2[mf][nt], 0, 0, 0);
                acc2[mf][nt] = __builtin_amdgcn_mfma_f32_16x16x32_bf16(al2[mf], bh[nt], acc2[mf][nt], 0, 0, 0);
            }
#pragma unroll
        for (int mf = 0; mf < 2; mf++) { ah2[mf] = ahn[mf]; al2[mf] = aln[mf]; }
    }

    // ---- score epilogue ----
    float rpart = 0.f;
    float cpart[4] = {0.f, 0.f, 0.f, 0.f};
#pragma unroll
    for (int mf = 0; mf < 2; mf++) {
        int o = 32 * w + 16 * mf + q * 4;
#pragma unroll
        for (int r = 0; r < 4; r++) {
            float bias = b2[o + r];
            float wcv = w_col[(o + r) * N_ + hrow];
#pragma unroll
            for (int nt = 0; nt < 4; nt++) {
                int wc = nt * 16 + col;
                float v = fmaxf(acc2[mf][nt][r] + bias, 0.f);
                rpart += v * w_row[(o + r) * N_ + wc];
                cpart[nt] += v * wcv;
            }
        }
    }
#pragma unroll
    for (int off = 32; off; off >>= 1) rpart += __shfl_xor(rpart, off, 64);
    if (l == 0) atomicAdd(&row_red, rpart);
#pragma unroll
    for (int nt = 0; nt < 4; nt++) {
        float cp = cpart[nt];
        cp += __shfl_xor(cp, 16, 64);
        cp += __shfl_xor(cp, 32, 64);
        if (l < 16) atomicAdd(&col_red[nt * 16 + l], cp);
    }
    __syncthreads();
    if (t < 64) atomicAdd(&col_s[b * N_ + t], col_red[t]);
    if (t == 0) row_s[b * N_ + hrow] = b_row[0] + row_red;
}

// ---------------- K4: diff bitonic sort, register-resident P, shuffle-only ----------------
__global__ __launch_bounds__(256) void k4_diffsort(const float* __restrict__ row_s,
                                                   const float* __restrict__ col_s,
                                                   u16* __restrict__ prow_h, u16* __restrict__ prow_l,
                                                   u16* __restrict__ pcol_h, u16* __restrict__ pcol_l) {
    const int t = threadIdx.x;
    const int lane = t & 63, w = t >> 6;
    const int which = blockIdx.x & 1;
    const int b = blockIdx.x >> 1;
    const float* sc = which ? col_s : row_s;
    u16* Ph = which ? pcol_h : prow_h;
    u16* Pl = which ? pcol_l : prow_l;

    float xv = sc[b * 64 + lane];
    float P[16];
#pragma unroll
    for (int r = 0; r < 16; r++) P[r] = ((w * 16 + r) == lane) ? 1.f : 0.f;

#pragma unroll
    for (int bl = 0; bl < 6; bl++) {
#pragma unroll
        for (int ly = 0; ly <= bl; ly++) {
            const int sh = bl - ly;
            const int m = 1 << sh;
            float xp = __shfl_xor(xv, m, 64);
            int lower = ((lane >> sh) & 1) ^ 1;
            int swp = (lane >> (bl + 1)) & 1;
            float diff = (lower ^ swp) ? (xp - xv) : (xv - xp);
            float al = atanf(diff * STEEP) * INV_PI + 0.5f;
            xv = al * xv + (1.f - al) * xp;
#pragma unroll
            for (int r = 0; r < 16; r++) {
                float Pp = __shfl_xor(P[r], m, 64);
                P[r] = al * P[r] + (1.f - al) * Pp;
            }
        }
    }
#pragma unroll
    for (int r = 0; r < 16; r++) {
        float v = P[r];
        u16 h = f2bf(v);
        int row = w * 16 + r;
        Ph[(size_t)b * 4096 + row * 64 + lane] = h;
        Pl[(size_t)b * 4096 + row * 64 + lane] = f2bf(v - bf2f(h));
    }
}

// ---------------- K5: double permutation, SWAPPED-operand MFMAs (R6 form) ----------------
// mfma(B,A) = (A*B)^T with identical operand reads; transposed D makes r the fastest
// output index: Z writes pack to ds_write_b64, out stores to dwordx4. cvt_pk packs
// the staging + Z conversions. (R7's 16x16x16 register chain reverted: legacy shape
// runs at half FLOP-rate -> GEMM2 cycles doubled, rest +8us.)
__global__ __launch_bounds__(256) void k5_permute(const float* __restrict__ x,
                                                  const u16* __restrict__ pcol_h,
                                                  const u16* __restrict__ pcol_l,
                                                  const u16* __restrict__ prow_h,
                                                  const u16* __restrict__ prow_l,
                                                  float* __restrict__ out) {
    __shared__ __align__(16) u16 Xh[64 * LDX];
    __shared__ __align__(16) u16 Xl[64 * LDX];
    __shared__ __align__(16) u16 Zh[64 * LDX];
    __shared__ __align__(16) u16 Zl[64 * LDX];
    const int t = threadIdx.x;
    const int l = t & 63, w = t >> 6;
    const int col = l & 15, q = l >> 4;
    const int b = blockIdx.y;
    const int cbase = blockIdx.x * 4;
    const int i0 = w * 16;

    const u16* pch = pcol_h + (size_t)b * 4096;
    const u16* pcl = pcol_l + (size_t)b * 4096;
    const u16* prh = prow_h + (size_t)b * 4096;
    const u16* prl = prow_l + (size_t)b * 4096;

    // hoisted P_col frags (GEMM1 2nd operand) and P_row frags (GEMM2 1st operand)
    bf16x8 pcA_h[2], pcA_l[2];
#pragma unroll
    for (int ks = 0; ks < 2; ks++) {
        pcA_h[ks] = *(const bf16x8*)&pch[(i0 + col) * 64 + q * 8 + ks * 32];
        pcA_l[ks] = *(const bf16x8*)&pcl[(i0 + col) * 64 + q * 8 + ks * 32];
    }
    bf16x8 prA_h[2][4], prA_l[2][4];
#pragma unroll
    for (int ks = 0; ks < 2; ks++)
#pragma unroll
        for (int ntj = 0; ntj < 4; ntj++) {
            prA_h[ks][ntj] = *(const bf16x8*)&prh[(ntj * 16 + col) * 64 + q * 8 + ks * 32];
            prA_l[ks][ntj] = *(const bf16x8*)&prl[(ntj * 16 + col) * 64 + q * 8 + ks * 32];
        }

    for (int ci = 0; ci < 4; ci++) {
        const int c = cbase + ci;
        const float* xc = x + ((size_t)b * C_ + c) * PIX_;
#pragma unroll
        for (int k = 0; k < 4; k++) {
            int f = t + k * 256;
            int rw = f >> 4, c4 = f & 15;
            float4 v = *(const float4*)&xc[f * 4];
            u32 h01 = cvtpk(v.x, v.y), h23 = cvtpk(v.z, v.w);
            u32 l01 = cvtpk(v.x - lo_f(h01), v.y - hi_f(h01));
            u32 l23 = cvtpk(v.z - lo_f(h23), v.w - hi_f(h23));
            *(u64*)&Xh[rw * LDX + c4 * 4] = (u64)h01 | ((u64)h23 << 32);
            *(u64*)&Xl[rw * LDX + c4 * 4] = (u64)l01 | ((u64)l23 << 32);
        }
        __syncthreads();

        // ---- GEMM1 (swapped): acc[ntx][r] = Z[i0+col][ntx*16+q*4+r] ----
        f32x4 acc[4];
#pragma unroll
        for (int nt = 0; nt < 4; nt++) acc[nt] = (f32x4){0.f, 0.f, 0.f, 0.f};
#pragma unroll
        for (int ks = 0; ks < 2; ks++) {
            bf16x8 ph = pcA_h[ks], pl = pcA_l[ks];
#pragma unroll
            for (int nt = 0; nt < 4; nt++) {
                bf16x8 xh8 = *(const bf16x8*)&Xh[(nt * 16 + col) * LDX + q * 8 + ks * 32];
                bf16x8 xl8 = *(const bf16x8*)&Xl[(nt * 16 + col) * LDX + q * 8 + ks * 32];
                acc[nt] = __builtin_amdgcn_mfma_f32_16x16x32_bf16(xh8, ph, acc[nt], 0, 0, 0);
                acc[nt] = __builtin_amdgcn_mfma_f32_16x16x32_bf16(xl8, ph, acc[nt], 0, 0, 0);
                acc[nt] = __builtin_amdgcn_mfma_f32_16x16x32_bf16(xh8, pl, acc[nt], 0, 0, 0);
            }
        }
        // ---- packed Z write (wave-private rows; compiler inserts lgkm wait) ----
#pragma unroll
        for (int nt = 0; nt < 4; nt++) {
            u32 h01 = cvtpk(acc[nt][0], acc[nt][1]), h23 = cvtpk(acc[nt][2], acc[nt][3]);
            u32 l01 = cvtpk(acc[nt][0] - lo_f(h01), acc[nt][1] - hi_f(h01));
            u32 l23 = cvtpk(acc[nt][2] - lo_f(h23), acc[nt][3] - hi_f(h23));
            int zi = (i0 + col) * LDX + nt * 16 + q * 4;
            *(u64*)&Zh[zi] = (u64)h01 | ((u64)h23 << 32);
            *(u64*)&Zl[zi] = (u64)l01 | ((u64)l23 << 32);
        }

        // ---- GEMM2 (swapped): acc2[ntj][r] = out[i0+col][ntj*16+q*4+r] ----
        f32x4 acc2[4];
#pragma unroll
        for (int nt = 0; nt < 4; nt++) acc2[nt] = (f32x4){0.f, 0.f, 0.f, 0.f};
#pragma unroll
        for (int ks = 0; ks < 2; ks++) {
            bf16x8 zh8 = *(const bf16x8*)&Zh[(i0 + col) * LDX + q * 8 + ks * 32];
            bf16x8 zl8 = *(const bf16x8*)&Zl[(i0 + col) * LDX + q * 8 + ks * 32];
#pragma unroll
            for (int ntj = 0; ntj < 4; ntj++) {
                acc2[ntj] = __builtin_amdgcn_mfma_f32_16x16x32_bf16(prA_h[ks][ntj], zh8, acc2[ntj], 0, 0, 0);
                acc2[ntj] = __builtin_amdgcn_mfma_f32_16x16x32_bf16(prA_l[ks][ntj], zh8, acc2[ntj], 0, 0, 0);
                acc2[ntj] = __builtin_amdgcn_mfma_f32_16x16x32_bf16(prA_h[ks][ntj], zl8, acc2[ntj], 0, 0, 0);
            }
        }
        // ---- packed out store: float4 per (ntj) ----
        float* oc = out + ((size_t)b * C_ + c) * PIX_;
#pragma unroll
        for (int ntj = 0; ntj < 4; ntj++) {
            float4 vv = {acc2[ntj][0], acc2[ntj][1], acc2[ntj][2], acc2[ntj][3]};
            *(float4*)&oc[(i0 + col) * 64 + ntj * 16 + q * 4] = vv;
        }
        __syncthreads();
    }
}

extern "C" void kernel_launch(void* const* d_in, const int* in_sizes, int n_in,
                              void* d_out, int out_size, void* d_ws, size_t ws_size,
                              hipStream_t stream) {
    const float* x = (const float*)d_in[0];
    const float* w1 = (const float*)d_in[1];
    const float* b1 = (const float*)d_in[2];
    const float* w2 = (const float*)d_in[3];
    const float* b2 = (const float*)d_in[4];
    const float* w_row = (const float*)d_in[5];
    const float* b_row = (const float*)d_in[6];
    const float* w_col = (const float*)d_in[7];
    const float* b_col = (const float*)d_in[8];
    float* out = (float*)d_out;

    char* ws = (char*)d_ws;
    u16* w1h = (u16*)(ws);                   //  65536 B
    u16* w1l = (u16*)(ws + 65536);           //  65536 B
    u16* w2h = (u16*)(ws + 131072);          //  131072 B
    u16* w2l = (u16*)(ws + 262144);          //  131072 B
    float* row_s = (float*)(ws + 393216);    //  8192 B
    float* col_s = (float*)(ws + 401408);    //  8192 B
    u16* prow_h = (u16*)(ws + 409600);       //  262144 B
    u16* prow_l = (u16*)(ws + 671744);       //  262144 B
    u16* pcol_h = (u16*)(ws + 933888);       //  262144 B
    u16* pcol_l = (u16*)(ws + 1196032);      //  262144 B

    hipLaunchKernelGGL(k_prep, dim3(384), dim3(256), 0, stream, w1, w2, w1h, w1l, w2h, w2l,
                       col_s, b_col);
    hipLaunchKernelGGL(k12_fused, dim3(64, 32), dim3(512), 0, stream,
                       x, w1h, w1l, b1, w2h, w2l, b2, w_row, b_row, w_col, row_s, col_s);
    hipLaunchKernelGGL(k4_diffsort, dim3(64), dim3(256), 0, stream,
                       row_s, col_s, prow_h, prow_l, pcol_h, pcol_l);
    hipLaunchKernelGGL(k5_permute, dim3(32, 32), dim3(256), 0, stream,
                       x, pcol_h, pcol_l, prow_h, prow_l, out);
}